// Round 4
// baseline (582.324 us; speedup 1.0000x reference)
//
#include <hip/hip_runtime.h>
#include <math.h>

#define DIMC 1024
#define SEQ  2048
#define BATCH 4
#define NTOK 8192
#define HEADS 16
#define HD 64

typedef __attribute__((ext_vector_type(8))) short short8;
typedef __attribute__((ext_vector_type(4))) float f32x4;

#define GLDS(gp, lp) __builtin_amdgcn_global_load_lds(                        \
    (const __attribute__((address_space(1))) void*)(gp),                      \
    (__attribute__((address_space(3))) void*)(lp), 16, 0, 0)

__device__ __forceinline__ float bf2f(unsigned short u) {
    union { unsigned int i; float f; } v; v.i = ((unsigned int)u) << 16; return v.f;
}
__device__ __forceinline__ unsigned short f2bf(float f) {
    union { float f; unsigned int i; } v; v.f = f;
    unsigned int r = v.i + 0x7FFFu + ((v.i >> 16) & 1u);
    return (unsigned short)(r >> 16);
}
// pack 2 floats -> 2 bf16 (round-half-up; p~1.0, bias negligible)
__device__ __forceinline__ unsigned int pk2bf(float a, float b) {
    union { float f; unsigned int u; } ua, ub; ua.f = a; ub.f = b;
    return ((ua.u + 0x8000u) >> 16) | ((ub.u + 0x8000u) & 0xFFFF0000u);
}

// ---------------------------------------------------------------------------
__global__ __launch_bounds__(256)
void cvt_f32_bf16(const float* __restrict__ X, unsigned short* __restrict__ Y, int n)
{
    int i = blockIdx.x * 256 + threadIdx.x;
    if (i < n) Y[i] = f2bf(X[i]);
}

// batched fp32->bf16 for the 3 pointwise weights
__global__ __launch_bounds__(256)
void cvt3(const float* __restrict__ A0, const float* __restrict__ A1,
          const float* __restrict__ A2,
          unsigned short* __restrict__ B0, unsigned short* __restrict__ B1,
          unsigned short* __restrict__ B2)
{
    int z = blockIdx.y;
    const float* X = z == 0 ? A0 : z == 1 ? A1 : A2;
    unsigned short* Y = z == 0 ? B0 : z == 1 ? B1 : B2;
    int i = blockIdx.x * 256 + threadIdx.x;
    Y[i] = f2bf(X[i]);
}

// mask -> additive float bias
__global__ __launch_bounds__(256)
void maskbias(const int* __restrict__ mask, float* __restrict__ fb)
{
    int i = blockIdx.x * 256 + threadIdx.x;
    fb[i] = (mask[i] != 0) ? 0.0f : -1e30f;
}

// ---------------------------------------------------------------------------
// W [in][out] fp32 -> Wt [out][in] bf16, batched over 4 weights (z)
// ---------------------------------------------------------------------------
__global__ __launch_bounds__(256)
void transpose_cvt4(const float* __restrict__ W0, const float* __restrict__ W1,
                    const float* __restrict__ W2, const float* __restrict__ W3,
                    unsigned short* __restrict__ T0, unsigned short* __restrict__ T1,
                    unsigned short* __restrict__ T2, unsigned short* __restrict__ T3)
{
    int z = blockIdx.z;
    const float* W = z == 0 ? W0 : z == 1 ? W1 : z == 2 ? W2 : W3;
    unsigned short* Wt = z == 0 ? T0 : z == 1 ? T1 : z == 2 ? T2 : T3;
    __shared__ float T[32][33];
    int i0 = blockIdx.y * 32, o0 = blockIdx.x * 32;
    int c = threadIdx.x & 31, r4 = threadIdx.x >> 5;
#pragma unroll
    for (int p = 0; p < 4; ++p) {
        int r = r4 + p * 8;
        T[r][c] = W[(size_t)(i0 + r) * DIMC + o0 + c];
    }
    __syncthreads();
#pragma unroll
    for (int p = 0; p < 4; ++p) {
        int r = r4 + p * 8;
        Wt[(size_t)(o0 + r) * DIMC + i0 + c] = f2bf(T[c][r]);
    }
}

// ---------------------------------------------------------------------------
// bf16 MFMA GEMM core (m97 structure): C = act(A @ Bt^T + bias)
// A:[M=NTOK][K=1024], Bt:[N=1024][K], 128x128 tile, BK=32, 4 waves.
// ---------------------------------------------------------------------------
template<bool SILU, bool F32OUT>
__device__ __forceinline__
void gemm_core(const unsigned short* __restrict__ A,
               const unsigned short* __restrict__ Bt,
               const float* __restrict__ bias, void* __restrict__ Cout)
{
    __shared__ unsigned short As[128 * 32];
    __shared__ unsigned short Bs[128 * 32];
    const int tid = threadIdx.x;
    const int lane = tid & 63;
    const int quad = lane >> 4, l16 = lane & 15;
    const int wave = tid >> 6;
    const int wm = (wave & 1) * 64, wn = (wave >> 1) * 64;
    const int m0 = blockIdx.y * 128, n0 = blockIdx.x * 128;
    const int K = DIMC, N = DIMC;

    f32x4 acc[4][4];
#pragma unroll
    for (int i = 0; i < 4; ++i)
#pragma unroll
        for (int j = 0; j < 4; ++j) acc[i][j] = (f32x4)(0.0f);

    for (int k0 = 0; k0 < K; k0 += 32) {
#pragma unroll
        for (int t = 0; t < 2; ++t) {
            int o = (t * 256 + tid) * 8;
            int row = o >> 5, col = o & 31;
            GLDS(A  + (size_t)(m0 + row) * K + k0 + col, As + o);
            GLDS(Bt + (size_t)(n0 + row) * K + k0 + col, Bs + o);
        }
        __syncthreads();
        short8 af[4], bfb[4];
#pragma unroll
        for (int i = 0; i < 4; ++i)
            af[i] = *(const short8*)(As + (wm + i * 16 + l16) * 32 + quad * 8);
#pragma unroll
        for (int j = 0; j < 4; ++j)
            bfb[j] = *(const short8*)(Bs + (wn + j * 16 + l16) * 32 + quad * 8);
#pragma unroll
        for (int i = 0; i < 4; ++i)
#pragma unroll
            for (int j = 0; j < 4; ++j)
                acc[i][j] = __builtin_amdgcn_mfma_f32_16x16x32_bf16(af[i], bfb[j], acc[i][j], 0, 0, 0);
        __syncthreads();
    }

#pragma unroll
    for (int i = 0; i < 4; ++i) {
        int mrow = m0 + wm + i * 16 + quad * 4;
#pragma unroll
        for (int j = 0; j < 4; ++j) {
            int ncol = n0 + wn + j * 16 + l16;
            float bval = bias[ncol];
#pragma unroll
            for (int r = 0; r < 4; ++r) {
                float v = acc[i][j][r] + bval;
                if (SILU) v = v / (1.0f + __expf(-v));
                if (F32OUT)
                    ((float*)Cout)[(size_t)(mrow + r) * N + ncol] = v;
                else
                    ((unsigned short*)Cout)[(size_t)(mrow + r) * N + ncol] = f2bf(v);
            }
        }
    }
}

__global__ __launch_bounds__(256)
void gemm_qkv(const unsigned short* A,
              const unsigned short* B0, const unsigned short* B1, const unsigned short* B2,
              const float* b0, const float* b1, const float* b2,
              unsigned short* C0, unsigned short* C1, unsigned short* C2)
{
    int z = blockIdx.z;
    gemm_core<true, false>(A, z == 0 ? B0 : z == 1 ? B1 : B2,
                           z == 0 ? b0 : z == 1 ? b1 : b2,
                           z == 0 ? C0 : z == 1 ? C1 : C2);
}

__global__ __launch_bounds__(256)
void gemm_pw(const unsigned short* A0, const unsigned short* A1, const unsigned short* A2,
             const unsigned short* B0, const unsigned short* B1, const unsigned short* B2,
             const float* b0, const float* b1, const float* b2,
             unsigned short* C0, unsigned short* C1, unsigned short* C2)
{
    int z = blockIdx.z;
    gemm_core<false, false>(z == 0 ? A0 : z == 1 ? A1 : A2,
                            z == 0 ? B0 : z == 1 ? B1 : B2,
                            z == 0 ? b0 : z == 1 ? b1 : b2,
                            z == 0 ? C0 : z == 1 ? C1 : C2);
}

__global__ __launch_bounds__(256)
void gemm_wo(const unsigned short* A, const unsigned short* Bt,
             const float* bias, float* C)
{
    gemm_core<false, true>(A, Bt, bias, C);
}

// ---------------------------------------------------------------------------
// Depthwise conv k=3 pad=1 over seq + bias, batched over q/k/v (blockIdx.y)
// ---------------------------------------------------------------------------
__global__ __launch_bounds__(256)
void dwconv3(const unsigned short* __restrict__ qb, const unsigned short* __restrict__ kb,
             const unsigned short* __restrict__ vb,
             const float* __restrict__ dwq, const float* __restrict__ dwbq,
             const float* __restrict__ dwk, const float* __restrict__ dwbk,
             const float* __restrict__ dwv, const float* __restrict__ dwbv,
             unsigned short* __restrict__ o0, unsigned short* __restrict__ o1,
             unsigned short* __restrict__ o2)
{
    int z = blockIdx.y;
    const unsigned short* X = z == 0 ? qb : z == 1 ? kb : vb;
    const float* dw  = z == 0 ? dwq  : z == 1 ? dwk  : dwv;
    const float* dwb = z == 0 ? dwbq : z == 1 ? dwbk : dwbv;
    unsigned short* Y = z == 0 ? o0 : z == 1 ? o1 : o2;

    int idx = blockIdx.x * 256 + threadIdx.x;
    int c = idx & (DIMC - 1);
    int s = (idx >> 10) & (SEQ - 1);
    float w0 = dw[c * 3 + 0], w1 = dw[c * 3 + 1], w2 = dw[c * 3 + 2];
    float xm = (s > 0)       ? bf2f(X[idx - DIMC]) : 0.0f;
    float xc = bf2f(X[idx]);
    float xp = (s < SEQ - 1) ? bf2f(X[idx + DIMC]) : 0.0f;
    Y[idx] = f2bf(fmaf(w0, xm, fmaf(w1, xc, fmaf(w2, xp, dwb[c]))));
}

// ---------------------------------------------------------------------------
// Row L2 normalize, batched (y=0: q with folded softmax scale, y=1: k).
// ---------------------------------------------------------------------------
__global__ __launch_bounds__(256)
void l2norm2(unsigned short* __restrict__ Xq, unsigned short* __restrict__ Xk)
{
    unsigned short* X = blockIdx.y ? Xk : Xq;
    const float post = blockIdx.y ? 1.0f : 0.125f * 1.44269504088896f;
    unsigned short* p = X + (size_t)blockIdx.x * DIMC;
    ushort4 v = ((ushort4*)p)[threadIdx.x];
    float f0 = bf2f(v.x), f1 = bf2f(v.y), f2 = bf2f(v.z), f3 = bf2f(v.w);
    float s = f0 * f0 + f1 * f1 + f2 * f2 + f3 * f3;
#pragma unroll
    for (int off = 32; off; off >>= 1) s += __shfl_down(s, off, 64);
    __shared__ float part[4];
    if ((threadIdx.x & 63) == 0) part[threadIdx.x >> 6] = s;
    __syncthreads();
    float tot = part[0] + part[1] + part[2] + part[3];
    float inv = post / fmaxf(sqrtf(tot), 1e-12f);
    v.x = f2bf(f0 * inv); v.y = f2bf(f1 * inv);
    v.z = f2bf(f2 * inv); v.w = f2bf(f3 * inv);
    ((ushort4*)p)[threadIdx.x] = v;
}

// ---------------------------------------------------------------------------
// V [B,S,C] bf16 -> Vt [B*H][64][SEQ] bf16 (per-head transpose)
// ---------------------------------------------------------------------------
__global__ __launch_bounds__(256)
void vtrans(const unsigned short* __restrict__ V, unsigned short* __restrict__ Vt)
{
    __shared__ unsigned short T[64][65];
    int st = blockIdx.x, bh = blockIdx.y;
    int b = bh >> 4, h = bh & 15;
    int tid = threadIdx.x;
#pragma unroll
    for (int t = 0; t < 16; ++t) {
        int o = t * 256 + tid; int r = o >> 6, c = o & 63;
        T[r][c] = V[(size_t)(b * SEQ + st * 64 + r) * DIMC + h * HD + c];
    }
    __syncthreads();
#pragma unroll
    for (int t = 0; t < 16; ++t) {
        int o = t * 256 + tid; int r = o >> 6, c = o & 63;
        Vt[(size_t)bh * HD * SEQ + (size_t)r * SEQ + st * 64 + c] = T[c][r];
    }
}

// ---------------------------------------------------------------------------
// Flash attention v3: no-max softmax (l2norm-bounded scores, scale folded
// into q), S^T MFMA so P packs as b64 writes, XOR-swizzled LDS, Q frags in
// registers, DOUBLE-BUFFERED K/V staging with ONE barrier per k-tile.
// Grid (SEQ/128, B*H), 256 thr = 4 waves, 32 q/wave. LDS 48 KB -> 3 blk/CU.
// ---------------------------------------------------------------------------
__global__ __launch_bounds__(256)
void attn_mfma3(const unsigned short* __restrict__ Q,
                const unsigned short* __restrict__ Km,
                const unsigned short* __restrict__ Vt,
                const float* __restrict__ fbias,
                unsigned short* __restrict__ O)
{
    __shared__ unsigned short Ksb[2][64 * 64];   // [k][d], chunk-swizzled
    __shared__ unsigned short Vsb[2][64 * 64];   // [d][k], chunk-swizzled
    __shared__ unsigned short Ps[4][32 * 64];    // per-wave [q][k], swizzled
    const int tid = threadIdx.x, lane = tid & 63, wave = tid >> 6;
    const int quad = lane >> 4, l16 = lane & 15;
    const int qt = blockIdx.x, bh = blockIdx.y;
    const int b = bh >> 4, h = bh & 15;
    const size_t qkbase = (size_t)b * SEQ * DIMC + (size_t)h * HD;
    const size_t vtbase = (size_t)bh * HD * SEQ;
    const int qbaseW = qt * 128 + wave * 32;
    const int NT = SEQ / 64;

    // Q B-fragments: loop-invariant, straight from global.
    short8 aq[2][2];
#pragma unroll
    for (int sub = 0; sub < 2; ++sub)
#pragma unroll
        for (int hf = 0; hf < 2; ++hf)
            aq[sub][hf] = *(const short8*)(Q + qkbase +
                (size_t)(qbaseW + sub * 16 + l16) * DIMC + hf * 32 + quad * 8);

    // staging slot geometry (fixed per thread)
    const int sA = tid,        rA = sA >> 3, cA = (sA & 7) ^ (rA & 7);
    const int sB = 256 + tid,  rB = sB >> 3, cB = (sB & 7) ^ (rB & 7);

    // prologue: stage tile 0 into buffer 0
    {
        GLDS(Km + qkbase + (size_t)rA * DIMC + cA * 8, Ksb[0] + sA * 8);
        GLDS(Km + qkbase + (size_t)rB * DIMC + cB * 8, Ksb[0] + sB * 8);
        GLDS(Vt + vtbase + (size_t)rA * SEQ + cA * 8,  Vsb[0] + sA * 8);
        GLDS(Vt + vtbase + (size_t)rB * SEQ + cB * 8,  Vsb[0] + sB * 8);
    }

    f32x4 oacc[2][4];
#pragma unroll
    for (int s = 0; s < 2; ++s)
#pragma unroll
        for (int t = 0; t < 4; ++t) oacc[s][t] = (f32x4)(0.0f);
    float lsum[2] = {0.0f, 0.0f};

    unsigned short* Pw = Ps[wave];

    for (int kt = 0; kt < NT; ++kt) {
        const int cur = kt & 1;
        __syncthreads();   // publishes buffer `cur` (own GLDS drained pre-barrier)

        // prefetch next tile into the other buffer; drained at NEXT barrier
        if (kt + 1 < NT) {
            const size_t ko = qkbase + (size_t)(kt + 1) * 64 * DIMC;
            const size_t vo = vtbase + (size_t)(kt + 1) * 64;
            GLDS(Km + ko + (size_t)rA * DIMC + cA * 8, Ksb[cur ^ 1] + sA * 8);
            GLDS(Km + ko + (size_t)rB * DIMC + cB * 8, Ksb[cur ^ 1] + sB * 8);
            GLDS(Vt + vo + (size_t)rA * SEQ + cA * 8,  Vsb[cur ^ 1] + sA * 8);
            GLDS(Vt + vo + (size_t)rB * SEQ + cB * 8,  Vsb[cur ^ 1] + sB * 8);
        }

        const unsigned short* Ks = Ksb[cur];
        const unsigned short* Vs = Vsb[cur];

        // K A-frags + V B-frags (swizzled reads, conflict-free)
        short8 ak0[4], ak1[4], bv0[4], bv1[4];
#pragma unroll
        for (int t = 0; t < 4; ++t) {
            int row = t * 16 + l16, sw = row & 7;
            ak0[t] = *(const short8*)(Ks + row * 64 + ((quad ^ sw) * 8));
            ak1[t] = *(const short8*)(Ks + row * 64 + (((4 + quad) ^ sw) * 8));
            bv0[t] = *(const short8*)(Vs + row * 64 + ((quad ^ sw) * 8));
            bv1[t] = *(const short8*)(Vs + row * 64 + (((4 + quad) ^ sw) * 8));
        }

        // mask bias (depends on t, quad only)
        float4 fbv[4];
#pragma unroll
        for (int t = 0; t < 4; ++t)
            fbv[t] = *(const float4*)(fbias + (size_t)b * SEQ + kt * 64 + t * 16 + quad * 4);

#pragma unroll
        for (int sub = 0; sub < 2; ++sub) {
            // S^T tiles: rows k (t*16+quad*4+r), cols q (l16)
            f32x4 sacc[4];
#pragma unroll
            for (int t = 0; t < 4; ++t) sacc[t] = (f32x4)(0.0f);
#pragma unroll
            for (int t = 0; t < 4; ++t) {
                sacc[t] = __builtin_amdgcn_mfma_f32_16x16x32_bf16(ak0[t], aq[sub][0], sacc[t], 0, 0, 0);
                sacc[t] = __builtin_amdgcn_mfma_f32_16x16x32_bf16(ak1[t], aq[sub][1], sacc[t], 0, 0, 0);
            }
            const int prow = sub * 16 + l16;
            const int psw = prow & 7;
            float ls = 0.0f;
#pragma unroll
            for (int t = 0; t < 4; ++t) {
                float p0 = exp2f(sacc[t][0] + fbv[t].x);
                float p1 = exp2f(sacc[t][1] + fbv[t].y);
                float p2 = exp2f(sacc[t][2] + fbv[t].z);
                float p3 = exp2f(sacc[t][3] + fbv[t].w);
                ls += (p0 + p1) + (p2 + p3);
                uint2 w; w.x = pk2bf(p0, p1); w.y = pk2bf(p2, p3);
                int chunk = (t * 2 + (quad >> 1)) ^ psw;
                *(uint2*)(Pw + prow * 64 + chunk * 8 + (quad & 1) * 4) = w;
            }
            lsum[sub] += ls;
        }

        // PV: O[q][d] += P[q][k] @ V^T  (A=P from LDS, B=Vt frags)
#pragma unroll
        for (int sub = 0; sub < 2; ++sub) {
            const int prow = sub * 16 + l16;
            const int psw = prow & 7;
            short8 ap0 = *(const short8*)(Pw + prow * 64 + ((quad ^ psw) * 8));
            short8 ap1 = *(const short8*)(Pw + prow * 64 + (((4 + quad) ^ psw) * 8));
#pragma unroll
            for (int t = 0; t < 4; ++t) {
                oacc[sub][t] = __builtin_amdgcn_mfma_f32_16x16x32_bf16(ap0, bv0[t], oacc[sub][t], 0, 0, 0);
                oacc[sub][t] = __builtin_amdgcn_mfma_f32_16x16x32_bf16(ap1, bv1[t], oacc[sub][t], 0, 0, 0);
            }
        }
    }

    // epilogue: finish l (reduce over quads), write O
#pragma unroll
    for (int sub = 0; sub < 2; ++sub) {
        float l = lsum[sub];
        l += __shfl_xor(l, 16, 64);
        l += __shfl_xor(l, 32, 64);
#pragma unroll
        for (int r = 0; r < 4; ++r) {
            float lr = __shfl(l, (lane & 48) | (quad * 4 + r), 64);
            float inv = 1.0f / lr;
            int grow = qbaseW + sub * 16 + quad * 4 + r;
#pragma unroll
            for (int t = 0; t < 4; ++t)
                O[(size_t)(b * SEQ + grow) * DIMC + h * HD + t * 16 + l16] =
                    f2bf(oacc[sub][t][r] * inv);
        }
    }
}

// ---------------------------------------------------------------------------
extern "C" void kernel_launch(void* const* d_in, const int* in_sizes, int n_in,
                              void* d_out, int out_size, void* d_ws, size_t ws_size,
                              hipStream_t stream)
{
    const float* x    = (const float*)d_in[0];
    const int*   mask = (const int*)  d_in[1];
    const float* wq   = (const float*)d_in[2];
    const float* bq   = (const float*)d_in[3];
    const float* dwq  = (const float*)d_in[4];
    const float* dwbq = (const float*)d_in[5];
    const float* pwq  = (const float*)d_in[6];
    const float* pwbq = (const float*)d_in[7];
    const float* wk   = (const float*)d_in[8];
    const float* bk   = (const float*)d_in[9];
    const float* dwk  = (const float*)d_in[10];
    const float* dwbk = (const float*)d_in[11];
    const float* pwk  = (const float*)d_in[12];
    const float* pwbk = (const float*)d_in[13];
    const float* wv   = (const float*)d_in[14];
    const float* bv   = (const float*)d_in[15];
    const float* dwv  = (const float*)d_in[16];
    const float* dwbv = (const float*)d_in[17];
    const float* pwv  = (const float*)d_in[18];
    const float* pwbv = (const float*)d_in[19];
    const float* wo   = (const float*)d_in[20];
    const float* bo   = (const float*)d_in[21];

    float* out = (float*)d_out;
    const size_t NE = (size_t)NTOK * DIMC;
    const size_t WE = (size_t)DIMC * DIMC;
    unsigned short* xb  = (unsigned short*)d_ws;   // x bf16; later dwconv-q out; later attn out
    unsigned short* qb  = xb + NE;
    unsigned short* kb  = qb + NE;
    unsigned short* vb  = kb + NE;
    unsigned short* tbA = vb + NE;
    unsigned short* tbB = tbA + NE;
    unsigned short* vt  = tbB + NE;
    unsigned short* wtq = vt + NE;
    unsigned short* wtk = wtq + WE;
    unsigned short* wtv = wtk + WE;
    unsigned short* wto = wtv + WE;
    unsigned short* pq  = wto + WE;
    unsigned short* pk  = pq + WE;
    unsigned short* pv  = pk + WE;
    float* fbias = (float*)(pv + WE);

    const dim3 tgrid(32, 32, 4);
    const dim3 ggrid3(DIMC / 128, NTOK / 128, 3);
    const dim3 ggrid(DIMC / 128, NTOK / 128);
    const dim3 vgrid(SEQ / 64, BATCH * HEADS);
    const dim3 agrid(SEQ / 128, BATCH * HEADS);
    const int eblk = (int)(NE / 256);
    const int wblk = (int)(WE / 256);

    cvt_f32_bf16<<<eblk, 256, 0, stream>>>(x, xb, (int)NE);
    transpose_cvt4<<<tgrid, 256, 0, stream>>>(wq, wk, wv, wo, wtq, wtk, wtv, wto);
    cvt3<<<dim3(wblk, 3), 256, 0, stream>>>(pwq, pwk, pwv, pq, pk, pv);
    maskbias<<<NTOK / 256, 256, 0, stream>>>(mask, fbias);

    // q/k/v = silu(x @ w + b), batched
    gemm_qkv<<<ggrid3, 256, 0, stream>>>(xb, wtq, wtk, wtv, bq, bk, bv, qb, kb, vb);

    // depthwise (batched) -> {xb, tbA, tbB}; pointwise (batched) -> back to q/k/v
    dwconv3<<<dim3(eblk, 3), 256, 0, stream>>>(qb, kb, vb, dwq, dwbq, dwk, dwbk,
                                               dwv, dwbv, xb, tbA, tbB);
    gemm_pw<<<ggrid3, 256, 0, stream>>>(xb, tbA, tbB, pq, pk, pv,
                                        pwbq, pwbk, pwbv, qb, kb, vb);

    // l2 norm (q gets folded softmax scale * log2e)
    l2norm2<<<dim3(NTOK, 2), 256, 0, stream>>>(qb, kb);

    // V transpose, attention (out -> xb), final projection
    vtrans<<<vgrid, 256, 0, stream>>>(vb, vt);
    attn_mfma3<<<agrid, 256, 0, stream>>>(qb, kb, vt, fbias, xb);
    gemm_wo<<<ggrid, 256, 0, stream>>>(xb, wto, bo, out);
}

// Round 5
// 568.039 us; speedup vs baseline: 1.0251x; 1.0251x over previous
//
#include <hip/hip_runtime.h>
#include <hip/hip_bf16.h>
#include <math.h>

#define DIMC 1024
#define SEQ  2048
#define BATCH 4
#define NTOK 8192
#define HEADS 16
#define HD 64

typedef __attribute__((ext_vector_type(8))) short short8;
typedef __attribute__((ext_vector_type(4))) float f32x4;

#define GLDS(gp, lp) __builtin_amdgcn_global_load_lds(                        \
    (const __attribute__((address_space(1))) void*)(gp),                      \
    (__attribute__((address_space(3))) void*)(lp), 16, 0, 0)

__device__ __forceinline__ float bf2f(unsigned short u) {
    union { unsigned int i; float f; } v; v.i = ((unsigned int)u) << 16; return v.f;
}
__device__ __forceinline__ unsigned short f2bf(float f) {
    union { float f; unsigned int i; } v; v.f = f;
    unsigned int r = v.i + 0x7FFFu + ((v.i >> 16) & 1u);
    return (unsigned short)(r >> 16);
}
// HW packed f32x2 -> bf16x2 (v_cvt_pk_bf16_f32)
__device__ __forceinline__ unsigned int pk2bf(float a, float b) {
    __hip_bfloat162 h = __float22bfloat162_rn(make_float2(a, b));
    unsigned int u; __builtin_memcpy(&u, &h, 4); return u;
}

// ---------------------------------------------------------------------------
// Fused prep: x cvt | 3 pointwise-weight cvts | mask->bias. One flat grid.
// ---------------------------------------------------------------------------
__global__ __launch_bounds__(256)
void prep(const float* __restrict__ x,
          const float* __restrict__ pwq2, const float* __restrict__ pwk2,
          const float* __restrict__ pwv2, const int* __restrict__ mask,
          unsigned short* __restrict__ xb, unsigned short* __restrict__ pq,
          unsigned short* __restrict__ pk, unsigned short* __restrict__ pv,
          float* __restrict__ fb)
{
    const size_t NE = (size_t)NTOK * DIMC;
    const size_t WE = (size_t)DIMC * DIMC;
    size_t i = (size_t)blockIdx.x * 256 + threadIdx.x;
    if (i < NE) { xb[i] = f2bf(x[i]); return; }
    i -= NE;
    if (i < WE) { pq[i] = f2bf(pwq2[i]); return; }
    i -= WE;
    if (i < WE) { pk[i] = f2bf(pwk2[i]); return; }
    i -= WE;
    if (i < WE) { pv[i] = f2bf(pwv2[i]); return; }
    i -= WE;
    fb[i] = (mask[i] != 0) ? 0.0f : -1e30f;
}

// ---------------------------------------------------------------------------
// W [in][out] fp32 -> Wt [out][in] bf16, batched over 4 weights (z)
// ---------------------------------------------------------------------------
__global__ __launch_bounds__(256)
void transpose_cvt4(const float* __restrict__ W0, const float* __restrict__ W1,
                    const float* __restrict__ W2, const float* __restrict__ W3,
                    unsigned short* __restrict__ T0, unsigned short* __restrict__ T1,
                    unsigned short* __restrict__ T2, unsigned short* __restrict__ T3)
{
    int z = blockIdx.z;
    const float* W = z == 0 ? W0 : z == 1 ? W1 : z == 2 ? W2 : W3;
    unsigned short* Wt = z == 0 ? T0 : z == 1 ? T1 : z == 2 ? T2 : T3;
    __shared__ float T[32][33];
    int i0 = blockIdx.y * 32, o0 = blockIdx.x * 32;
    int c = threadIdx.x & 31, r4 = threadIdx.x >> 5;
#pragma unroll
    for (int p = 0; p < 4; ++p) {
        int r = r4 + p * 8;
        T[r][c] = W[(size_t)(i0 + r) * DIMC + o0 + c];
    }
    __syncthreads();
#pragma unroll
    for (int p = 0; p < 4; ++p) {
        int r = r4 + p * 8;
        Wt[(size_t)(o0 + r) * DIMC + i0 + c] = f2bf(T[c][r]);
    }
}

// ---------------------------------------------------------------------------
// bf16 MFMA GEMM core (m97 structure): C = act(A @ Bt^T + bias)
// ---------------------------------------------------------------------------
template<bool SILU, bool F32OUT>
__device__ __forceinline__
void gemm_core(const unsigned short* __restrict__ A,
               const unsigned short* __restrict__ Bt,
               const float* __restrict__ bias, void* __restrict__ Cout)
{
    __shared__ unsigned short As[128 * 32];
    __shared__ unsigned short Bs[128 * 32];
    const int tid = threadIdx.x;
    const int lane = tid & 63;
    const int quad = lane >> 4, l16 = lane & 15;
    const int wave = tid >> 6;
    const int wm = (wave & 1) * 64, wn = (wave >> 1) * 64;
    const int m0 = blockIdx.y * 128, n0 = blockIdx.x * 128;
    const int K = DIMC, N = DIMC;

    f32x4 acc[4][4];
#pragma unroll
    for (int i = 0; i < 4; ++i)
#pragma unroll
        for (int j = 0; j < 4; ++j) acc[i][j] = (f32x4)(0.0f);

    for (int k0 = 0; k0 < K; k0 += 32) {
#pragma unroll
        for (int t = 0; t < 2; ++t) {
            int o = (t * 256 + tid) * 8;
            int row = o >> 5, col = o & 31;
            GLDS(A  + (size_t)(m0 + row) * K + k0 + col, As + o);
            GLDS(Bt + (size_t)(n0 + row) * K + k0 + col, Bs + o);
        }
        __syncthreads();
        short8 af[4], bfb[4];
#pragma unroll
        for (int i = 0; i < 4; ++i)
            af[i] = *(const short8*)(As + (wm + i * 16 + l16) * 32 + quad * 8);
#pragma unroll
        for (int j = 0; j < 4; ++j)
            bfb[j] = *(const short8*)(Bs + (wn + j * 16 + l16) * 32 + quad * 8);
#pragma unroll
        for (int i = 0; i < 4; ++i)
#pragma unroll
            for (int j = 0; j < 4; ++j)
                acc[i][j] = __builtin_amdgcn_mfma_f32_16x16x32_bf16(af[i], bfb[j], acc[i][j], 0, 0, 0);
        __syncthreads();
    }

#pragma unroll
    for (int i = 0; i < 4; ++i) {
        int mrow = m0 + wm + i * 16 + quad * 4;
#pragma unroll
        for (int j = 0; j < 4; ++j) {
            int ncol = n0 + wn + j * 16 + l16;
            float bval = bias[ncol];
#pragma unroll
            for (int r = 0; r < 4; ++r) {
                float v = acc[i][j][r] + bval;
                if (SILU) v = v / (1.0f + __expf(-v));
                if (F32OUT)
                    ((float*)Cout)[(size_t)(mrow + r) * N + ncol] = v;
                else
                    ((unsigned short*)Cout)[(size_t)(mrow + r) * N + ncol] = f2bf(v);
            }
        }
    }
}

__global__ __launch_bounds__(256)
void gemm_qkv(const unsigned short* A,
              const unsigned short* B0, const unsigned short* B1, const unsigned short* B2,
              const float* b0, const float* b1, const float* b2,
              unsigned short* C0, unsigned short* C1, unsigned short* C2)
{
    int z = blockIdx.z;
    gemm_core<true, false>(A, z == 0 ? B0 : z == 1 ? B1 : B2,
                           z == 0 ? b0 : z == 1 ? b1 : b2,
                           z == 0 ? C0 : z == 1 ? C1 : C2);
}

__global__ __launch_bounds__(256)
void gemm_pw(const unsigned short* A0, const unsigned short* A1, const unsigned short* A2,
             const unsigned short* B0, const unsigned short* B1, const unsigned short* B2,
             const float* b0, const float* b1, const float* b2,
             unsigned short* C0, unsigned short* C1, unsigned short* C2)
{
    int z = blockIdx.z;
    gemm_core<false, false>(z == 0 ? A0 : z == 1 ? A1 : A2,
                            z == 0 ? B0 : z == 1 ? B1 : B2,
                            z == 0 ? b0 : z == 1 ? b1 : b2,
                            z == 0 ? C0 : z == 1 ? C1 : C2);
}

__global__ __launch_bounds__(256)
void gemm_wo(const unsigned short* A, const unsigned short* Bt,
             const float* bias, float* C)
{
    gemm_core<false, true>(A, Bt, bias, C);
}

// ---------------------------------------------------------------------------
// Depthwise conv k=3 pad=1 over seq + bias, batched over q/k/v (blockIdx.y)
// ---------------------------------------------------------------------------
__global__ __launch_bounds__(256)
void dwconv3(const unsigned short* __restrict__ qb, const unsigned short* __restrict__ kb,
             const unsigned short* __restrict__ vb,
             const float* __restrict__ dwq, const float* __restrict__ dwbq,
             const float* __restrict__ dwk, const float* __restrict__ dwbk,
             const float* __restrict__ dwv, const float* __restrict__ dwbv,
             unsigned short* __restrict__ o0, unsigned short* __restrict__ o1,
             unsigned short* __restrict__ o2)
{
    int z = blockIdx.y;
    const unsigned short* X = z == 0 ? qb : z == 1 ? kb : vb;
    const float* dw  = z == 0 ? dwq  : z == 1 ? dwk  : dwv;
    const float* dwb = z == 0 ? dwbq : z == 1 ? dwbk : dwbv;
    unsigned short* Y = z == 0 ? o0 : z == 1 ? o1 : o2;

    int idx = blockIdx.x * 256 + threadIdx.x;
    int c = idx & (DIMC - 1);
    int s = (idx >> 10) & (SEQ - 1);
    float w0 = dw[c * 3 + 0], w1 = dw[c * 3 + 1], w2 = dw[c * 3 + 2];
    float xm = (s > 0)       ? bf2f(X[idx - DIMC]) : 0.0f;
    float xc = bf2f(X[idx]);
    float xp = (s < SEQ - 1) ? bf2f(X[idx + DIMC]) : 0.0f;
    Y[idx] = f2bf(fmaf(w0, xm, fmaf(w1, xc, fmaf(w2, xp, dwb[c]))));
}

// ---------------------------------------------------------------------------
// Per-token inverse L2 norms (no rewrite of q/k). y=0: q (with 0.125*log2e
// folded), y=1: k. One block per row.
// ---------------------------------------------------------------------------
__global__ __launch_bounds__(256)
void rownorms(const unsigned short* __restrict__ qb, const unsigned short* __restrict__ kb,
              float* __restrict__ qsc, float* __restrict__ ksc)
{
    const unsigned short* X = (blockIdx.y ? kb : qb) + (size_t)blockIdx.x * DIMC;
    ushort4 v = ((const ushort4*)X)[threadIdx.x];
    float f0 = bf2f(v.x), f1 = bf2f(v.y), f2 = bf2f(v.z), f3 = bf2f(v.w);
    float s = f0 * f0 + f1 * f1 + f2 * f2 + f3 * f3;
#pragma unroll
    for (int off = 32; off; off >>= 1) s += __shfl_down(s, off, 64);
    __shared__ float part[4];
    if ((threadIdx.x & 63) == 0) part[threadIdx.x >> 6] = s;
    __syncthreads();
    if (threadIdx.x == 0) {
        float tot = part[0] + part[1] + part[2] + part[3];
        float post = blockIdx.y ? 1.0f : 0.125f * 1.44269504088896f;
        float inv = post / fmaxf(sqrtf(tot), 1e-12f);
        (blockIdx.y ? ksc : qsc)[blockIdx.x] = inv;
    }
}

// ---------------------------------------------------------------------------
// V [B,S,C] bf16 -> Vt [B*H][64][SEQ] bf16 (per-head transpose)
// ---------------------------------------------------------------------------
__global__ __launch_bounds__(256)
void vtrans(const unsigned short* __restrict__ V, unsigned short* __restrict__ Vt)
{
    __shared__ unsigned short T[64][65];
    int st = blockIdx.x, bh = blockIdx.y;
    int b = bh >> 4, h = bh & 15;
    int tid = threadIdx.x;
#pragma unroll
    for (int t = 0; t < 16; ++t) {
        int o = t * 256 + tid; int r = o >> 6, c = o & 63;
        T[r][c] = V[(size_t)(b * SEQ + st * 64 + r) * DIMC + h * HD + c];
    }
    __syncthreads();
#pragma unroll
    for (int t = 0; t < 16; ++t) {
        int o = t * 256 + tid; int r = o >> 6, c = o & 63;
        Vt[(size_t)bh * HD * SEQ + (size_t)r * SEQ + st * 64 + c] = T[c][r];
    }
}

// ---------------------------------------------------------------------------
// Flash attention v4: no-max exp2 softmax with l2norm folded in as score
// scaling (p = exp2(fma(s, invq*invk, maskbias))); l computed by MFMA with
// ones-B (same C-layout as oacc -> shuffle-free epilogue); HW bf16 pack;
// S^T MFMA; XOR-swizzled LDS; double-buffered K/V; one barrier per k-tile.
// Grid (SEQ/128, B*H), 256 thr = 4 waves, 32 q/wave.
// ---------------------------------------------------------------------------
__global__ __launch_bounds__(256)
void attn_mfma4(const unsigned short* __restrict__ Q,
                const unsigned short* __restrict__ Km,
                const unsigned short* __restrict__ Vt,
                const float* __restrict__ qscale,
                const float* __restrict__ kscale,
                const float* __restrict__ fbias,
                unsigned short* __restrict__ O)
{
    __shared__ unsigned short Ksb[2][64 * 64];   // [k][d], chunk-swizzled
    __shared__ unsigned short Vsb[2][64 * 64];   // [d][k], chunk-swizzled
    __shared__ unsigned short Ps[4][32 * 64];    // per-wave [q][k], swizzled
    const int tid = threadIdx.x, lane = tid & 63, wave = tid >> 6;
    const int quad = lane >> 4, l16 = lane & 15;
    const int qt = blockIdx.x, bh = blockIdx.y;
    const int b = bh >> 4, h = bh & 15;
    const size_t qkbase = (size_t)b * SEQ * DIMC + (size_t)h * HD;
    const size_t vtbase = (size_t)bh * HD * SEQ;
    const int qbaseW = qt * 128 + wave * 32;
    const int NT = SEQ / 64;

    // Q B-fragments + per-lane q scales: loop-invariant.
    short8 aq[2][2];
    float qsc[2];
#pragma unroll
    for (int sub = 0; sub < 2; ++sub) {
        qsc[sub] = qscale[b * SEQ + qbaseW + sub * 16 + l16];
#pragma unroll
        for (int hf = 0; hf < 2; ++hf)
            aq[sub][hf] = *(const short8*)(Q + qkbase +
                (size_t)(qbaseW + sub * 16 + l16) * DIMC + hf * 32 + quad * 8);
    }

    short8 vone;
#pragma unroll
    for (int i = 0; i < 8; ++i) vone[i] = (short)0x3F80;   // bf16 1.0

    // staging slot geometry (fixed per thread)
    const int sA = tid,        rA = sA >> 3, cA = (sA & 7) ^ (rA & 7);
    const int sB = 256 + tid,  rB = sB >> 3, cB = (sB & 7) ^ (rB & 7);

    // prologue: stage tile 0 into buffer 0
    GLDS(Km + qkbase + (size_t)rA * DIMC + cA * 8, Ksb[0] + sA * 8);
    GLDS(Km + qkbase + (size_t)rB * DIMC + cB * 8, Ksb[0] + sB * 8);
    GLDS(Vt + vtbase + (size_t)rA * SEQ + cA * 8,  Vsb[0] + sA * 8);
    GLDS(Vt + vtbase + (size_t)rB * SEQ + cB * 8,  Vsb[0] + sB * 8);

    f32x4 oacc[2][4], lacc[2];
#pragma unroll
    for (int s = 0; s < 2; ++s) {
        lacc[s] = (f32x4)(0.0f);
#pragma unroll
        for (int t = 0; t < 4; ++t) oacc[s][t] = (f32x4)(0.0f);
    }

    unsigned short* Pw = Ps[wave];

    for (int kt = 0; kt < NT; ++kt) {
        const int cur = kt & 1;
        __syncthreads();   // publishes buffer `cur`

        if (kt + 1 < NT) {
            const size_t ko = qkbase + (size_t)(kt + 1) * 64 * DIMC;
            const size_t vo = vtbase + (size_t)(kt + 1) * 64;
            GLDS(Km + ko + (size_t)rA * DIMC + cA * 8, Ksb[cur ^ 1] + sA * 8);
            GLDS(Km + ko + (size_t)rB * DIMC + cB * 8, Ksb[cur ^ 1] + sB * 8);
            GLDS(Vt + vo + (size_t)rA * SEQ + cA * 8,  Vsb[cur ^ 1] + sA * 8);
            GLDS(Vt + vo + (size_t)rB * SEQ + cB * 8,  Vsb[cur ^ 1] + sB * 8);
        }

        const unsigned short* Ks = Ksb[cur];
        const unsigned short* Vs = Vsb[cur];

        // K A-frags + V B-frags (swizzled, conflict-free)
        short8 ak0[4], ak1[4], bv0[4], bv1[4];
#pragma unroll
        for (int t = 0; t < 4; ++t) {
            int row = t * 16 + l16, sw = row & 7;
            ak0[t] = *(const short8*)(Ks + row * 64 + ((quad ^ sw) * 8));
            ak1[t] = *(const short8*)(Ks + row * 64 + (((4 + quad) ^ sw) * 8));
            bv0[t] = *(const short8*)(Vs + row * 64 + ((quad ^ sw) * 8));
            bv1[t] = *(const short8*)(Vs + row * 64 + (((4 + quad) ^ sw) * 8));
        }

        // per-k-row scale & mask bias (rows t*16 + quad*4 + r)
        float4 ksv[4], fbv[4];
#pragma unroll
        for (int t = 0; t < 4; ++t) {
            size_t off = (size_t)b * SEQ + kt * 64 + t * 16 + quad * 4;
            ksv[t] = *(const float4*)(kscale + off);
            fbv[t] = *(const float4*)(fbias + off);
        }

#pragma unroll
        for (int sub = 0; sub < 2; ++sub) {
            // S^T tiles: rows k (t*16+quad*4+r), cols q (l16)
            f32x4 sacc[4];
#pragma unroll
            for (int t = 0; t < 4; ++t) sacc[t] = (f32x4)(0.0f);
#pragma unroll
            for (int t = 0; t < 4; ++t) {
                sacc[t] = __builtin_amdgcn_mfma_f32_16x16x32_bf16(ak0[t], aq[sub][0], sacc[t], 0, 0, 0);
                sacc[t] = __builtin_amdgcn_mfma_f32_16x16x32_bf16(ak1[t], aq[sub][1], sacc[t], 0, 0, 0);
            }
            const int prow = sub * 16 + l16;
            const int psw = prow & 7;
            const float qs = qsc[sub];
#pragma unroll
            for (int t = 0; t < 4; ++t) {
                float p0 = exp2f(fmaf(sacc[t][0], qs * ksv[t].x, fbv[t].x));
                float p1 = exp2f(fmaf(sacc[t][1], qs * ksv[t].y, fbv[t].y));
                float p2 = exp2f(fmaf(sacc[t][2], qs * ksv[t].z, fbv[t].z));
                float p3 = exp2f(fmaf(sacc[t][3], qs * ksv[t].w, fbv[t].w));
                uint2 w; w.x = pk2bf(p0, p1); w.y = pk2bf(p2, p3);
                int chunk = (t * 2 + (quad >> 1)) ^ psw;
                *(uint2*)(Pw + prow * 64 + chunk * 8 + (quad & 1) * 4) = w;
            }
        }

        // PV + l: O[q][d] += P@V^T ; l[q] += P@ones (same C-layout as oacc)
#pragma unroll
        for (int sub = 0; sub < 2; ++sub) {
            const int prow = sub * 16 + l16;
            const int psw = prow & 7;
            short8 ap0 = *(const short8*)(Pw + prow * 64 + ((quad ^ psw) * 8));
            short8 ap1 = *(const short8*)(Pw + prow * 64 + (((4 + quad) ^ psw) * 8));
#pragma unroll
            for (int t = 0; t < 4; ++t) {
                oacc[sub][t] = __builtin_amdgcn_mfma_f32_16x16x32_bf16(ap0, bv0[t], oacc[sub][t], 0, 0, 0);
                oacc[sub][t] = __builtin_amdgcn_mfma_f32_16x16x32_bf16(ap1, bv1[t], oacc[sub][t], 0, 0, 0);
            }
            lacc[sub] = __builtin_amdgcn_mfma_f32_16x16x32_bf16(ap0, vone, lacc[sub], 0, 0, 0);
            lacc[sub] = __builtin_amdgcn_mfma_f32_16x16x32_bf16(ap1, vone, lacc[sub], 0, 0, 0);
        }
    }

    // epilogue: lacc rows match oacc rows exactly -> no shuffles
#pragma unroll
    for (int sub = 0; sub < 2; ++sub)
#pragma unroll
        for (int r = 0; r < 4; ++r) {
            float inv = 1.0f / lacc[sub][r];
            int grow = qbaseW + sub * 16 + quad * 4 + r;
#pragma unroll
            for (int t = 0; t < 4; ++t)
                O[(size_t)(b * SEQ + grow) * DIMC + h * HD + t * 16 + l16] =
                    f2bf(oacc[sub][t][r] * inv);
        }
}

// ---------------------------------------------------------------------------
extern "C" void kernel_launch(void* const* d_in, const int* in_sizes, int n_in,
                              void* d_out, int out_size, void* d_ws, size_t ws_size,
                              hipStream_t stream)
{
    const float* x    = (const float*)d_in[0];
    const int*   mask = (const int*)  d_in[1];
    const float* wq   = (const float*)d_in[2];
    const float* bq   = (const float*)d_in[3];
    const float* dwq  = (const float*)d_in[4];
    const float* dwbq = (const float*)d_in[5];
    const float* pwq  = (const float*)d_in[6];
    const float* pwbq = (const float*)d_in[7];
    const float* wk   = (const float*)d_in[8];
    const float* bk   = (const float*)d_in[9];
    const float* dwk  = (const float*)d_in[10];
    const float* dwbk = (const float*)d_in[11];
    const float* pwk  = (const float*)d_in[12];
    const float* pwbk = (const float*)d_in[13];
    const float* wv   = (const float*)d_in[14];
    const float* bv   = (const float*)d_in[15];
    const float* dwv  = (const float*)d_in[16];
    const float* dwbv = (const float*)d_in[17];
    const float* pwv  = (const float*)d_in[18];
    const float* pwbv = (const float*)d_in[19];
    const float* wo   = (const float*)d_in[20];
    const float* bo   = (const float*)d_in[21];

    float* out = (float*)d_out;
    const size_t NE = (size_t)NTOK * DIMC;
    const size_t WE = (size_t)DIMC * DIMC;
    unsigned short* xb  = (unsigned short*)d_ws;   // x bf16; later dwconv-q out; later attn out
    unsigned short* qb  = xb + NE;
    unsigned short* kb  = qb + NE;
    unsigned short* vb  = kb + NE;
    unsigned short* tbA = vb + NE;
    unsigned short* tbB = tbA + NE;
    unsigned short* vt  = tbB + NE;
    unsigned short* wtq = vt + NE;
    unsigned short* wtk = wtq + WE;
    unsigned short* wtv = wtk + WE;
    unsigned short* wto = wtv + WE;
    unsigned short* pq  = wto + WE;
    unsigned short* pk  = pq + WE;
    unsigned short* pv  = pk + WE;
    float* fbias  = (float*)(pv + WE);
    float* qscale = fbias + NTOK;
    float* kscale = qscale + NTOK;

    const dim3 tgrid(32, 32, 4);
    const dim3 ggrid3(DIMC / 128, NTOK / 128, 3);
    const dim3 ggrid(DIMC / 128, NTOK / 128);
    const dim3 vgrid(SEQ / 64, BATCH * HEADS);
    const dim3 agrid(SEQ / 128, BATCH * HEADS);
    const int eblk = (int)(NE / 256);
    const int pblk = (int)((NE + 3 * WE + NTOK) / 256);

    prep<<<pblk, 256, 0, stream>>>(x, pwq, pwk, pwv, mask, xb, pq, pk, pv, fbias);
    transpose_cvt4<<<tgrid, 256, 0, stream>>>(wq, wk, wv, wo, wtq, wtk, wtv, wto);

    // q/k/v = silu(x @ w + b), batched
    gemm_qkv<<<ggrid3, 256, 0, stream>>>(xb, wtq, wtk, wtv, bq, bk, bv, qb, kb, vb);

    // depthwise (batched) -> {xb, tbA, tbB}; pointwise (batched) -> back to q/k/v
    dwconv3<<<dim3(eblk, 3), 256, 0, stream>>>(qb, kb, vb, dwq, dwbq, dwk, dwbk,
                                               dwv, dwbv, xb, tbA, tbB);
    gemm_pw<<<ggrid3, 256, 0, stream>>>(xb, tbA, tbB, pq, pk, pv,
                                        pwbq, pwbk, pwbv, qb, kb, vb);

    // per-token inverse norms (l2norm folded into attention score scaling)
    rownorms<<<dim3(NTOK, 2), 256, 0, stream>>>(qb, kb, qscale, kscale);

    // V transpose, attention (out -> xb), final projection
    vtrans<<<vgrid, 256, 0, stream>>>(vb, vt);
    attn_mfma4<<<agrid, 256, 0, stream>>>(qb, kb, vt, qscale, kscale, fbias, xb);
    gemm_wo<<<ggrid, 256, 0, stream>>>(xb, wto, bo, out);
}